// Round 6
// baseline (128.212 us; speedup 1.0000x reference)
//
#include <hip/hip_runtime.h>
#include <hip/hip_bf16.h>

#define NIMG 4
#define CCH  32
#define PPIX 131072          // 256*512
#define KLBL 16

#define K1_CHUNK 8192
#define K1_NCHUNK (PPIX / K1_CHUNK)   // 16
#define K2_CHUNK 1024
#define K2_NCHUNK (PPIX / K2_CHUNK)   // 128

__device__ __forceinline__ float wave_sum(float v) {
#pragma unroll
    for (int m = 1; m < 64; m <<= 1) v += __shfl_xor(v, m);
    return v;
}

// Kernel 1: mu_raw[n][c][k] = sum_p feat[n,c,p] * (gt[n,p]==k)
// 2 channels per block; per-thread 2x16 register accumulators (compile-time indexed).
__global__ __launch_bounds__(256) void k1_mu(const float* __restrict__ feat,
                                             const int* __restrict__ gt,
                                             float* __restrict__ mu_raw) {
    int b     = blockIdx.x;
    int chunk = b % K1_NCHUNK;
    int cpair = (b / K1_NCHUNK) % (CCH / 2);
    int n     = b / (K1_NCHUNK * (CCH / 2));
    int c0    = cpair * 2;
    int p0    = chunk * K1_CHUNK;
    int tid   = threadIdx.x;

    const float* f0 = feat + ((size_t)(n * CCH + c0)) * PPIX + p0;
    const float* f1 = f0 + PPIX;
    const int*   g  = gt + (size_t)n * PPIX + p0;

    float acc0[KLBL], acc1[KLBL];
#pragma unroll
    for (int k = 0; k < KLBL; k++) { acc0[k] = 0.f; acc1[k] = 0.f; }

    for (int i = tid * 4; i < K1_CHUNK; i += 256 * 4) {
        float4 a  = *(const float4*)(f0 + i);
        float4 bb = *(const float4*)(f1 + i);
        int4   l  = *(const int4*)(g + i);
#pragma unroll
        for (int k = 0; k < KLBL; k++) {
            float mx = (l.x == k) ? 1.f : 0.f;
            float my = (l.y == k) ? 1.f : 0.f;
            float mz = (l.z == k) ? 1.f : 0.f;
            float mw = (l.w == k) ? 1.f : 0.f;
            acc0[k] = fmaf(a.x,  mx, acc0[k]);  acc1[k] = fmaf(bb.x, mx, acc1[k]);
            acc0[k] = fmaf(a.y,  my, acc0[k]);  acc1[k] = fmaf(bb.y, my, acc1[k]);
            acc0[k] = fmaf(a.z,  mz, acc0[k]);  acc1[k] = fmaf(bb.z, mz, acc1[k]);
            acc0[k] = fmaf(a.w,  mw, acc0[k]);  acc1[k] = fmaf(bb.w, mw, acc1[k]);
        }
    }

    __shared__ float warr[4][32];
    int wave = tid >> 6, lane = tid & 63;
#pragma unroll
    for (int k = 0; k < KLBL; k++) {
        float s0 = wave_sum(acc0[k]);
        float s1 = wave_sum(acc1[k]);
        if (lane == 0) { warr[wave][k] = s0; warr[wave][16 + k] = s1; }
    }
    __syncthreads();
    if (tid < 32) {
        float t = warr[0][tid] + warr[1][tid] + warr[2][tid] + warr[3][tid];
        int ch = tid >> 4, k = tid & 15;
        atomicAdd(&mu_raw[(n * CCH + c0 + ch) * KLBL + k], t);
    }
}

// Kernel 2: per-pixel ||f_p - mu[:, gt[p]]||, accumulated per (n,k), plus counts.
__global__ __launch_bounds__(256) void k2_var(const float* __restrict__ feat,
                                              const int* __restrict__ gt,
                                              const float* __restrict__ mu_raw,
                                              float* __restrict__ sumd,
                                              float* __restrict__ cnt) {
    __shared__ float lmu[CCH * KLBL];
    int b     = blockIdx.x;
    int chunk = b % K2_NCHUNK;
    int n     = b / K2_NCHUNK;
    int p0    = chunk * K2_CHUNK;
    int tid   = threadIdx.x;

    const float inv_p = 1.0f / (float)PPIX;
#pragma unroll
    for (int i = tid; i < CCH * KLBL; i += 256)
        lmu[i] = mu_raw[n * CCH * KLBL + i] * inv_p;
    __syncthreads();

    int p = p0 + tid * 4;
    int4 l = *(const int4*)(gt + (size_t)n * PPIX + p);
    float d2x = 0.f, d2y = 0.f, d2z = 0.f, d2w = 0.f;
    const float* fb = feat + (size_t)n * CCH * PPIX + p;
#pragma unroll 8
    for (int c = 0; c < CCH; c++) {
        float4 f = *(const float4*)(fb + (size_t)c * PPIX);
        float mx = lmu[c * KLBL + l.x];
        float my = lmu[c * KLBL + l.y];
        float mz = lmu[c * KLBL + l.z];
        float mw = lmu[c * KLBL + l.w];
        float ex = f.x - mx, ey = f.y - my, ez = f.z - mz, ew = f.w - mw;
        d2x = fmaf(ex, ex, d2x); d2y = fmaf(ey, ey, d2y);
        d2z = fmaf(ez, ez, d2z); d2w = fmaf(ew, ew, d2w);
    }
    float dx = sqrtf(d2x), dy = sqrtf(d2y), dz = sqrtf(d2z), dw = sqrtf(d2w);

    float s[KLBL], ct[KLBL];
#pragma unroll
    for (int k = 0; k < KLBL; k++) {
        float mx = (l.x == k) ? 1.f : 0.f;
        float my = (l.y == k) ? 1.f : 0.f;
        float mz = (l.z == k) ? 1.f : 0.f;
        float mw = (l.w == k) ? 1.f : 0.f;
        s[k]  = fmaf(dx, mx, fmaf(dy, my, fmaf(dz, mz, dw * mw)));
        ct[k] = mx + my + mz + mw;
    }

    __shared__ float warr[4][32];
    int wave = tid >> 6, lane = tid & 63;
#pragma unroll
    for (int k = 0; k < KLBL; k++) {
        float ssum = wave_sum(s[k]);
        float csum = wave_sum(ct[k]);
        if (lane == 0) { warr[wave][k] = ssum; warr[wave][16 + k] = csum; }
    }
    __syncthreads();
    if (tid < 32) {
        float t = warr[0][tid] + warr[1][tid] + warr[2][tid] + warr[3][tid];
        if (tid < 16) atomicAdd(&sumd[n * KLBL + tid], t);
        else          atomicAdd(&cnt[n * KLBL + (tid - 16)], t);
    }
}

// Kernel 3: finalize — losses + mu output. 256 threads for the mu copy;
// sqmu write and loss math separated by a uniform __syncthreads().
__global__ __launch_bounds__(256) void k3_final(const float* __restrict__ mu_raw,
                                                const float* __restrict__ sumd,
                                                const float* __restrict__ cnt,
                                                float* __restrict__ out) {
    __shared__ float mu[NIMG * CCH * KLBL];
    __shared__ float sqmu[NIMG * KLBL];
    int t = threadIdx.x;
    const float inv_p = 1.0f / (float)PPIX;
    for (int i = t; i < NIMG * CCH * KLBL; i += 256) {
        float m = mu_raw[i] * inv_p;
        mu[i]   = m;
        out[4 + i] = m;
    }
    __syncthreads();

    float sq = 0.f;
    if (t < 64) {
        int n = t >> 4, k = t & 15;
#pragma unroll
        for (int c = 0; c < CCH; c++) {
            float m = mu[(n * CCH + c) * KLBL + k];
            sq = fmaf(m, m, sq);
        }
        sqmu[t] = sq;
    }
    __syncthreads();   // uniform: all 256 threads reach this

    if (t < 64) {
        int n = t >> 4, k = t & 15;
        float dsum = 0.f;
#pragma unroll
        for (int j = 0; j < KLBL; j++) {
            if (j == k) continue;
            float gram = 0.f;
#pragma unroll
            for (int c = 0; c < CCH; c++)
                gram = fmaf(mu[(n * CCH + c) * KLBL + k], mu[(n * CCH + c) * KLBL + j], gram);
            float sqd = sq + sqmu[n * KLBL + j] - 2.f * gram;
            dsum += (sqd > 0.f) ? sqrtf(sqd) : 0.f;
        }
        float dist_term = fmaxf(2.f * 0.2f - dsum * (1.f / (KLBL - 1)), 0.f);
        float sqm = (sq > 0.f) ? sqrtf(sq) : 0.f;
        float v = (sumd[t] + ((float)PPIX - cnt[t]) * sqm) * inv_p;
        float var_term = fmaxf(v - 0.2f, 0.f);

        float d_r = wave_sum(dist_term);
        float v_r = wave_sum(var_term);
        float n_r = wave_sum(sqm);
        if (t == 0) {
            float variance_loss      = v_r * (1.f / (NIMG * KLBL));
            float distance_loss      = d_r * (1.f / (NIMG * KLBL));
            float normalization_loss = n_r * (1.f / (NIMG * KLBL));
            out[0] = variance_loss + distance_loss + 0.001f * normalization_loss;
            out[1] = variance_loss;
            out[2] = distance_loss;
            out[3] = normalization_loss;
        }
    }
}

extern "C" void kernel_launch(void* const* d_in, const int* in_sizes, int n_in,
                              void* d_out, int out_size, void* d_ws, size_t ws_size,
                              hipStream_t stream) {
    const float* feat = (const float*)d_in[0];
    const int*   gt   = (const int*)d_in[1];
    float* out    = (float*)d_out;
    float* mu_raw = (float*)d_ws;                       // 2048 floats
    float* sumd   = mu_raw + NIMG * CCH * KLBL;         // 64 floats
    float* cntp   = sumd + NIMG * KLBL;                 // 64 floats

    hipMemsetAsync(d_ws, 0, (NIMG * CCH * KLBL + 2 * NIMG * KLBL) * sizeof(float), stream);

    k1_mu<<<NIMG * (CCH / 2) * K1_NCHUNK, 256, 0, stream>>>(feat, gt, mu_raw);
    k2_var<<<NIMG * K2_NCHUNK, 256, 0, stream>>>(feat, gt, mu_raw, sumd, cntp);
    k3_final<<<1, 256, 0, stream>>>(mu_raw, sumd, cntp, out);
}